// Round 9
// baseline (321.957 us; speedup 1.0000x reference)
//
#include <hip/hip_runtime.h>
#include <hip/hip_bf16.h>
#include <stdint.h>

#define NN 50000
#define NE 625000
#define DD 128
#define NL 3
#define GB 391  // gemm blocks = ceil(NN/128)

typedef __bf16 bf16x8 __attribute__((ext_vector_type(8)));
typedef float f32x4 __attribute__((ext_vector_type(4)));

__device__ __forceinline__ float bflo(uint32_t u) { return __uint_as_float(u << 16); }
__device__ __forceinline__ float bfhi(uint32_t u) { return __uint_as_float(u & 0xffff0000u); }
__device__ __forceinline__ uint16_t f2bf(float f) {
    __hip_bfloat16 h = __float2bfloat16(f);
    return __builtin_bit_cast(uint16_t, h);
}
__device__ __forceinline__ uint32_t pack2(float lo, float hi) {
    return (uint32_t)f2bf(lo) | ((uint32_t)f2bf(hi) << 16);
}

// ---------------- CSR construction ----------------
__global__ void k_hist(const int* __restrict__ dstv, int* __restrict__ deg) {
    int e = blockIdx.x * 256 + threadIdx.x;
    if (e < NE) atomicAdd(&deg[dstv[e]], 1);
}

// single-pass scan: block-local exclusive prefix + atomic global base.
__global__ __launch_bounds__(512) void k_scan1(int* __restrict__ cursor /* deg in, rowbeg out */,
                                               int* __restrict__ rowptr,
                                               int* __restrict__ rowend,
                                               int* __restrict__ gcount) {
    __shared__ int s[512];
    __shared__ int base;
    int t = threadIdx.x;
    int i = blockIdx.x * 512 + t;
    int v = (i < NN) ? cursor[i] : 0;
    s[t] = v;
    __syncthreads();
    for (int st = 1; st < 512; st <<= 1) {
        int a = (t >= st) ? s[t - st] : 0;
        __syncthreads();
        s[t] += a;
        __syncthreads();
    }
    if (t == 511) base = atomicAdd(gcount, s[511]);
    __syncthreads();
    if (i < NN) {
        int b = base + s[t] - v;
        rowptr[i] = b;
        rowend[i] = b + v;
        cursor[i] = b;  // fill cursor
    }
}

__global__ void k_fill(const int* __restrict__ srcv, const int* __restrict__ dstv,
                       int* __restrict__ cursor, int* __restrict__ colv) {
    int e = blockIdx.x * 256 + threadIdx.x;
    if (e < NE) {
        int d = dstv[e];
        int p = atomicAdd(&cursor[d], 1);
        colv[p] = srcv[e];
    }
}

// ---------------- merged prep: weight convert + x->bf16 + cursor/gcount/bnsum zero ----------------
#define WCONV_BLOCKS 576  // 9*16384/256
__global__ void k_prep(const float* __restrict__ x, uint16_t* __restrict__ hb,
                       int* __restrict__ cursor, int* __restrict__ gcount,
                       float* __restrict__ bnsum,
                       const float* __restrict__ W1, const float* __restrict__ W2,
                       const float* __restrict__ Wl, uint16_t* __restrict__ Wb) {
    int b = blockIdx.x;
    if (b < WCONV_BLOCKS) {
        int id = b * 256 + threadIdx.x;
        int m = id >> 14;
        int r = id & 16383;
        int k = r >> 7;
        int col = r & 127;
        const float* src;
        if (m < 3) src = W1 + m * 16384;
        else if (m < 6) src = W2 + (m - 3) * 16384;
        else src = Wl + (m - 6) * 16384;
        float v = src[k * 128 + col];
        // image layout: [col][k] with k-index XOR-swizzled by (col&7)<<3 (bf16 units)
        Wb[m * 16384 + col * 128 + (k ^ ((col & 7) << 3))] = f2bf(v);
        return;
    }
    int id = (b - WCONV_BLOCKS) * 256 + threadIdx.x;
    if (id == 0) *gcount = 0;
    if (id < NL * 256) bnsum[id] = 0.f;  // per-layer BN stats slots
    if (id < NN) cursor[id] = 0;
    int base = id * 4;
    if (base >= NN * DD) return;
    float4 v = *(const float4*)(x + base);
    uint2 st;
    st.x = pack2(v.x, v.y);
    st.y = pack2(v.z, v.w);
    *(uint2*)(hb + base) = st;
}

// ---------------- fused agg + MLP ----------------
// Block owns rows [brow, brow+128). Warp w's threads (2 per node) gather rows
// m0..m0+31 and write the z image into the warp-private ldsT quarter; GEMM1
// A-reads the same quarter (no barrier needed for ldsT). ldsW barriers as before.
__global__ __launch_bounds__(256) void k_aggmlp(const uint16_t* __restrict__ hb,
                                                const int* __restrict__ rowptr,
                                                const int* __restrict__ rowend,
                                                const int* __restrict__ colv,
                                                const float* __restrict__ epsp, int layer,
                                                const uint16_t* __restrict__ W1img,
                                                const uint16_t* __restrict__ W2img,
                                                const float* __restrict__ b1,
                                                const float* __restrict__ b2,
                                                float* __restrict__ bnsum,
                                                uint16_t* __restrict__ z2b) {
    __shared__ uint16_t ldsW[16384];  // 32KB: W1 -> W2
    __shared__ uint16_t ldsT[16384];  // 32KB: z image -> t1 image -> stats scratch
    int tid = threadIdx.x;
    int wid = tid >> 6, lane = tid & 63;
    const int brow = blockIdx.x * 128;

    // stage W1 image (barrier deferred past the gather)
#pragma unroll
    for (int it = 0; it < 8; ++it) {
        int idx = (it * 256 + tid) * 8;
        *(bf16x8*)(&ldsW[idx]) = *(const bf16x8*)(W1img + idx);
    }

    // ---- gather: 2 threads per node, 64 columns each, edges unrolled x2 ----
    int row = tid >> 1, half = tid & 1;
    int g = brow + row;
    float a[64];
#pragma unroll
    for (int i = 0; i < 64; ++i) a[i] = 0.f;
    if (g < NN) {
        float onepe = 1.0f + epsp[layer];
        int beg = rowptr[g], end = rowend[g];
        const uint4* hp = (const uint4*)hb + half * 8;  // column base offset
        int j = beg;
        for (; j + 1 < end; j += 2) {
            int s0 = colv[j];
            int s1 = colv[j + 1];
            const uint4* r0 = hp + (size_t)s0 * 16;
            const uint4* r1 = hp + (size_t)s1 * 16;
            uint4 u[8], v[8];
#pragma unroll
            for (int i = 0; i < 8; ++i) u[i] = r0[i];
#pragma unroll
            for (int i = 0; i < 8; ++i) v[i] = r1[i];
#pragma unroll
            for (int i = 0; i < 8; ++i) {
                a[i * 8 + 0] += bflo(u[i].x); a[i * 8 + 1] += bfhi(u[i].x);
                a[i * 8 + 2] += bflo(u[i].y); a[i * 8 + 3] += bfhi(u[i].y);
                a[i * 8 + 4] += bflo(u[i].z); a[i * 8 + 5] += bfhi(u[i].z);
                a[i * 8 + 6] += bflo(u[i].w); a[i * 8 + 7] += bfhi(u[i].w);
            }
#pragma unroll
            for (int i = 0; i < 8; ++i) {
                a[i * 8 + 0] += bflo(v[i].x); a[i * 8 + 1] += bfhi(v[i].x);
                a[i * 8 + 2] += bflo(v[i].y); a[i * 8 + 3] += bfhi(v[i].y);
                a[i * 8 + 4] += bflo(v[i].z); a[i * 8 + 5] += bfhi(v[i].z);
                a[i * 8 + 6] += bflo(v[i].w); a[i * 8 + 7] += bfhi(v[i].w);
            }
        }
        if (j < end) {
            int s0 = colv[j];
            const uint4* r0 = hp + (size_t)s0 * 16;
            uint4 u[8];
#pragma unroll
            for (int i = 0; i < 8; ++i) u[i] = r0[i];
#pragma unroll
            for (int i = 0; i < 8; ++i) {
                a[i * 8 + 0] += bflo(u[i].x); a[i * 8 + 1] += bfhi(u[i].x);
                a[i * 8 + 2] += bflo(u[i].y); a[i * 8 + 3] += bfhi(u[i].y);
                a[i * 8 + 4] += bflo(u[i].z); a[i * 8 + 5] += bfhi(u[i].z);
                a[i * 8 + 6] += bflo(u[i].w); a[i * 8 + 7] += bfhi(u[i].w);
            }
        }
        // self term
        {
            const uint4* rs = hp + (size_t)g * 16;
            uint4 u[8];
#pragma unroll
            for (int i = 0; i < 8; ++i) u[i] = rs[i];
#pragma unroll
            for (int i = 0; i < 8; ++i) {
                a[i * 8 + 0] = fmaf(onepe, bflo(u[i].x), a[i * 8 + 0]);
                a[i * 8 + 1] = fmaf(onepe, bfhi(u[i].x), a[i * 8 + 1]);
                a[i * 8 + 2] = fmaf(onepe, bflo(u[i].y), a[i * 8 + 2]);
                a[i * 8 + 3] = fmaf(onepe, bfhi(u[i].y), a[i * 8 + 3]);
                a[i * 8 + 4] = fmaf(onepe, bflo(u[i].z), a[i * 8 + 4]);
                a[i * 8 + 5] = fmaf(onepe, bfhi(u[i].z), a[i * 8 + 5]);
                a[i * 8 + 6] = fmaf(onepe, bflo(u[i].w), a[i * 8 + 6]);
                a[i * 8 + 7] = fmaf(onepe, bfhi(u[i].w), a[i * 8 + 7]);
            }
        }
    }
    // write z image (bf16) into warp-private ldsT quarter; zeros for tail rows
    {
        int swz = (row & 7) << 4;
#pragma unroll
        for (int i = 0; i < 8; ++i) {
            uint4 st;
            st.x = pack2(a[i * 8 + 0], a[i * 8 + 1]);
            st.y = pack2(a[i * 8 + 2], a[i * 8 + 3]);
            st.z = pack2(a[i * 8 + 4], a[i * 8 + 5]);
            st.w = pack2(a[i * 8 + 6], a[i * 8 + 7]);
            *(uint4*)((char*)ldsT + row * 256 + ((half * 128 + i * 16) ^ swz)) = st;
        }
    }
    __syncthreads();  // ldsW (W1) staged by all warps

    const int m0 = wid * 32;
    const int l15 = lane & 15;
    const int lhi = lane >> 4;

    f32x4 acc[2][8];
    f32x4 zero = {0.f, 0.f, 0.f, 0.f};
#pragma unroll
    for (int m = 0; m < 2; ++m)
#pragma unroll
        for (int n = 0; n < 8; ++n) acc[m][n] = zero;

    // ---- GEMM1: A from ldsT z-image, B = W1 ----
#pragma unroll
    for (int kk = 0; kk < 4; ++kk) {
        int kbyte = kk * 64 + (lhi << 4);
        bf16x8 afrag[2];
#pragma unroll
        for (int m = 0; m < 2; ++m) {
            int rowl = m0 + m * 16 + l15;
            afrag[m] = *(const bf16x8*)((const char*)ldsT + rowl * 256 + (kbyte ^ ((rowl & 7) << 4)));
        }
#pragma unroll
        for (int n = 0; n < 8; ++n) {
            int col = n * 16 + l15;
            int addr = col * 256 + (kbyte ^ ((col & 7) << 4));
            bf16x8 bfrag = *(const bf16x8*)((const char*)ldsW + addr);
            acc[0][n] = __builtin_amdgcn_mfma_f32_16x16x32_bf16(afrag[0], bfrag, acc[0][n], 0, 0, 0);
            acc[1][n] = __builtin_amdgcn_mfma_f32_16x16x32_bf16(afrag[1], bfrag, acc[1][n], 0, 0, 0);
        }
    }

    // ---- epilogue1: relu(acc + b1) -> ldsT (warp-private quarter, image layout) ----
    {
        float bc[8];
#pragma unroll
        for (int n = 0; n < 8; ++n) bc[n] = b1[n * 16 + l15];
#pragma unroll
        for (int m = 0; m < 2; ++m) {
            int rbase = m0 + m * 16 + (lhi << 2);
#pragma unroll
            for (int r = 0; r < 4; ++r) {
                int rw = rbase + r;
#pragma unroll
                for (int n = 0; n < 8; ++n) {
                    float v = fmaxf(acc[m][n][r] + bc[n], 0.f);
                    int col = n * 16 + l15;
                    int byteoff = rw * 256 + ((col * 2) ^ ((rw & 7) << 4));
                    *(uint16_t*)((char*)ldsT + byteoff) = f2bf(v);
                }
            }
        }
    }
    __syncthreads();  // all warps done reading W1 from ldsW

    // stage W2
#pragma unroll
    for (int it = 0; it < 8; ++it) {
        int idx = (it * 256 + tid) * 8;
        *(bf16x8*)(&ldsW[idx]) = *(const bf16x8*)(W2img + idx);
    }
    __syncthreads();

    // ---- GEMM2: A from ldsT t1-image, B = W2 ----
#pragma unroll
    for (int m = 0; m < 2; ++m)
#pragma unroll
        for (int n = 0; n < 8; ++n) acc[m][n] = zero;

#pragma unroll
    for (int kk = 0; kk < 4; ++kk) {
        int kbyte = kk * 64 + (lhi << 4);
        bf16x8 afrag[2];
#pragma unroll
        for (int m = 0; m < 2; ++m) {
            int rowl = m0 + m * 16 + l15;
            afrag[m] = *(const bf16x8*)((const char*)ldsT + rowl * 256 + (kbyte ^ ((rowl & 7) << 4)));
        }
#pragma unroll
        for (int n = 0; n < 8; ++n) {
            int col = n * 16 + l15;
            int addr = col * 256 + (kbyte ^ ((col & 7) << 4));
            bf16x8 bfrag = *(const bf16x8*)((const char*)ldsW + addr);
            acc[0][n] = __builtin_amdgcn_mfma_f32_16x16x32_bf16(afrag[0], bfrag, acc[0][n], 0, 0, 0);
            acc[1][n] = __builtin_amdgcn_mfma_f32_16x16x32_bf16(afrag[1], bfrag, acc[1][n], 0, 0, 0);
        }
    }

    // ---- epilogue2: z2 (bf16) + BN stats from exact f32 ----
    float bc2[8];
#pragma unroll
    for (int n = 0; n < 8; ++n) bc2[n] = b2[n * 16 + l15];

    float s1[8], s2[8];
#pragma unroll
    for (int n = 0; n < 8; ++n) { s1[n] = 0.f; s2[n] = 0.f; }

#pragma unroll
    for (int m = 0; m < 2; ++m) {
        int rbase = brow + m0 + m * 16 + (lhi << 2);
#pragma unroll
        for (int r = 0; r < 4; ++r) {
            int rw = rbase + r;
            bool ok = rw < NN;
#pragma unroll
            for (int n = 0; n < 8; ++n) {
                float v = acc[m][n][r] + bc2[n];
                if (ok) {
                    z2b[(size_t)rw * 128 + n * 16 + l15] = f2bf(v);
                    s1[n] += v;
                    s2[n] += v * v;
                }
            }
        }
    }

    __syncthreads();  // ldsT A-reads done; reuse for stats
    float* ls = (float*)ldsT;
    ls[tid] = 0.f;
    __syncthreads();
#pragma unroll
    for (int n = 0; n < 8; ++n) {
        float a1 = s1[n] + __shfl_xor(s1[n], 16);
        a1 += __shfl_xor(a1, 32);
        float a2 = s2[n] + __shfl_xor(s2[n], 16);
        a2 += __shfl_xor(a2, 32);
        if (lane < 16) {
            atomicAdd(&ls[n * 16 + lane], a1);
            atomicAdd(&ls[128 + n * 16 + lane], a2);
        }
    }
    __syncthreads();
    atomicAdd(&bnsum[tid], ls[tid]);
}

// ---------------- fused BN-apply + skip + relu -> hnext + out GEMM ----------------
// Block owns rows [brow, brow+128). Apply phase writes hnext image into the
// warp-private ldsT quarter; GEMM A-reads the same quarter.
__global__ __launch_bounds__(256) void k_applyout(const uint16_t* __restrict__ z2b,
                                                  const uint16_t* __restrict__ hin,
                                                  const float* __restrict__ bnsumL,
                                                  const float* __restrict__ gammal,
                                                  const float* __restrict__ betal,
                                                  int has_skip,
                                                  const uint16_t* __restrict__ Wlimg,
                                                  const float* __restrict__ blv,
                                                  uint16_t* __restrict__ hout,
                                                  float* __restrict__ outl) {
    __shared__ uint16_t ldsW[16384];  // Wl image
    __shared__ uint16_t ldsT[16384];  // hnext image
    __shared__ float sAB[256];
    int tid = threadIdx.x;
    int wid = tid >> 6, lane = tid & 63;
    const int brow = blockIdx.x * 128;

    // stage Wl image
#pragma unroll
    for (int it = 0; it < 8; ++it) {
        int idx = (it * 256 + tid) * 8;
        *(bf16x8*)(&ldsW[idx]) = *(const bf16x8*)(Wlimg + idx);
    }
    if (tid < 128) {
        float mu = bnsumL[tid] * (1.0f / NN);
        float var = bnsumL[128 + tid] * (1.0f / NN) - mu * mu;
        float aa = gammal[tid] * rsqrtf(var + 1e-5f);
        sAB[tid] = aa;
        sAB[128 + tid] = betal[tid] - mu * aa;
    }
    __syncthreads();

    // ---- apply: 2 threads per row, 64 columns each ----
    int row = tid >> 1, half = tid & 1;
    int g = brow + row;
    {
        int swz = (row & 7) << 4;
        if (g < NN) {
            const uint4* zrow = (const uint4*)(z2b + (size_t)g * 128) + half * 8;
            const uint4* hrow = (const uint4*)(hin + (size_t)g * 128) + half * 8;
            uint4* orow = (uint4*)(hout + (size_t)g * 128) + half * 8;
            uint4 zu[8], hu[8];
#pragma unroll
            for (int i = 0; i < 8; ++i) zu[i] = zrow[i];
            if (has_skip) {
#pragma unroll
                for (int i = 0; i < 8; ++i) hu[i] = hrow[i];
            }
#pragma unroll
            for (int i = 0; i < 8; ++i) {
                int c0 = half * 64 + i * 8;
                float v[8];
                v[0] = fmaf(sAB[c0 + 0], bflo(zu[i].x), sAB[128 + c0 + 0]);
                v[1] = fmaf(sAB[c0 + 1], bfhi(zu[i].x), sAB[128 + c0 + 1]);
                v[2] = fmaf(sAB[c0 + 2], bflo(zu[i].y), sAB[128 + c0 + 2]);
                v[3] = fmaf(sAB[c0 + 3], bfhi(zu[i].y), sAB[128 + c0 + 3]);
                v[4] = fmaf(sAB[c0 + 4], bflo(zu[i].z), sAB[128 + c0 + 4]);
                v[5] = fmaf(sAB[c0 + 5], bfhi(zu[i].z), sAB[128 + c0 + 5]);
                v[6] = fmaf(sAB[c0 + 6], bflo(zu[i].w), sAB[128 + c0 + 6]);
                v[7] = fmaf(sAB[c0 + 7], bfhi(zu[i].w), sAB[128 + c0 + 7]);
                if (has_skip) {
                    v[0] += bflo(hu[i].x); v[1] += bfhi(hu[i].x);
                    v[2] += bflo(hu[i].y); v[3] += bfhi(hu[i].y);
                    v[4] += bflo(hu[i].z); v[5] += bfhi(hu[i].z);
                    v[6] += bflo(hu[i].w); v[7] += bfhi(hu[i].w);
                }
#pragma unroll
                for (int k = 0; k < 8; ++k) v[k] = fmaxf(v[k], 0.f);
                uint4 st;
                st.x = pack2(v[0], v[1]);
                st.y = pack2(v[2], v[3]);
                st.z = pack2(v[4], v[5]);
                st.w = pack2(v[6], v[7]);
                orow[i] = st;  // hnext global (linear)
                *(uint4*)((char*)ldsT + row * 256 + ((half * 128 + i * 16) ^ swz)) = st;
            }
        } else {
            uint4 zz = {0, 0, 0, 0};
#pragma unroll
            for (int i = 0; i < 8; ++i)
                *(uint4*)((char*)ldsT + row * 256 + ((half * 128 + i * 16) ^ swz)) = zz;
        }
    }
    // no barrier needed: warp-private ldsT quarters (warp w: rows w*32..w*32+31)

    const int m0 = wid * 32;
    const int l15 = lane & 15;
    const int lhi = lane >> 4;

    f32x4 acc[2][8];
    f32x4 zero = {0.f, 0.f, 0.f, 0.f};
#pragma unroll
    for (int m = 0; m < 2; ++m)
#pragma unroll
        for (int n = 0; n < 8; ++n) acc[m][n] = zero;

    // ---- GEMM: A from ldsT hnext-image, B = Wl ----
#pragma unroll
    for (int kk = 0; kk < 4; ++kk) {
        int kbyte = kk * 64 + (lhi << 4);
        bf16x8 afrag[2];
#pragma unroll
        for (int m = 0; m < 2; ++m) {
            int rowl = m0 + m * 16 + l15;
            afrag[m] = *(const bf16x8*)((const char*)ldsT + rowl * 256 + (kbyte ^ ((rowl & 7) << 4)));
        }
#pragma unroll
        for (int n = 0; n < 8; ++n) {
            int col = n * 16 + l15;
            int addr = col * 256 + (kbyte ^ ((col & 7) << 4));
            bf16x8 bfrag = *(const bf16x8*)((const char*)ldsW + addr);
            acc[0][n] = __builtin_amdgcn_mfma_f32_16x16x32_bf16(afrag[0], bfrag, acc[0][n], 0, 0, 0);
            acc[1][n] = __builtin_amdgcn_mfma_f32_16x16x32_bf16(afrag[1], bfrag, acc[1][n], 0, 0, 0);
        }
    }

    float bc3[8];
#pragma unroll
    for (int n = 0; n < 8; ++n) bc3[n] = blv[n * 16 + l15];

#pragma unroll
    for (int m = 0; m < 2; ++m) {
        int rbase = brow + m0 + m * 16 + (lhi << 2);
#pragma unroll
        for (int r = 0; r < 4; ++r) {
            int rw = rbase + r;
            if (rw < NN) {
#pragma unroll
                for (int n = 0; n < 8; ++n) {
                    outl[(size_t)rw * (NL * DD) + n * 16 + l15] = acc[m][n][r] + bc3[n];
                }
            }
        }
    }
}

extern "C" void kernel_launch(void* const* d_in, const int* in_sizes, int n_in,
                              void* d_out, int out_size, void* d_ws, size_t ws_size,
                              hipStream_t stream) {
    const float* x = (const float*)d_in[0];
    const int* ei = (const int*)d_in[1];
    const float* W1 = (const float*)d_in[2];
    const float* b1 = (const float*)d_in[3];
    const float* W2 = (const float*)d_in[4];
    const float* b2 = (const float*)d_in[5];
    const float* epsp = (const float*)d_in[6];
    const float* gamma = (const float*)d_in[7];
    const float* beta = (const float*)d_in[8];
    const float* Wl = (const float*)d_in[9];
    const float* bl = (const float*)d_in[10];
    float* out = (float*)d_out;

    char* w = (char*)d_ws;
    size_t off = 0;
    auto take = [&](size_t b) -> char* {
        char* p = w + off;
        off += (b + 255) & ~(size_t)255;
        return p;
    };
    uint16_t* hb[4];
    for (int i = 0; i < 4; ++i) hb[i] = (uint16_t*)take((size_t)NN * DD * 2);
    uint16_t* z2b = (uint16_t*)take((size_t)NN * DD * 2);
    int* rowptr = (int*)take((size_t)NN * 4);
    int* rowend = (int*)take((size_t)NN * 4);
    int* cursor = (int*)take((size_t)NN * 4);
    int* colv = (int*)take((size_t)NE * 4);
    uint16_t* Wb = (uint16_t*)take(9 * 16384 * 2);
    float* bnsum = (float*)take(NL * 256 * 4);
    int* gcount = (int*)take(256);

    const int* srcv = ei;        // edge_index[0]
    const int* dstv = ei + NE;   // edge_index[1]

    // merged prep: weight convert + x->bf16 + cursor/gcount/bnsum zero
    const int x2bf_blocks = (NN * DD / 4 + 255) / 256;  // 6250
    k_prep<<<WCONV_BLOCKS + x2bf_blocks, 256, 0, stream>>>(x, hb[0], cursor, gcount, bnsum,
                                                           W1, W2, Wl, Wb);

    // CSR build
    k_hist<<<(NE + 255) / 256, 256, 0, stream>>>(dstv, cursor);
    k_scan1<<<98, 512, 0, stream>>>(cursor, rowptr, rowend, gcount);
    k_fill<<<(NE + 255) / 256, 256, 0, stream>>>(srcv, dstv, cursor, colv);

    for (int l = 0; l < NL; ++l) {
        k_aggmlp<<<GB, 256, 0, stream>>>(hb[l], rowptr, rowend, colv, epsp, l,
                                         Wb + l * 16384, Wb + (3 + l) * 16384,
                                         b1 + l * 128, b2 + l * 128,
                                         bnsum + l * 256, z2b);
        k_applyout<<<GB, 256, 0, stream>>>(z2b, hb[l], bnsum + l * 256,
                                           gamma + l * 128, beta + l * 128,
                                           l > 0 ? 1 : 0,
                                           Wb + (6 + l) * 16384, bl + l * 128,
                                           hb[l + 1], out + l * 128);
    }
}

// Round 10
// 260.177 us; speedup vs baseline: 1.2375x; 1.2375x over previous
//
#include <hip/hip_runtime.h>
#include <hip/hip_bf16.h>
#include <stdint.h>

#define NN 50000
#define NE 625000
#define DD 128
#define NL 3
#define GB 391  // gemm blocks = ceil(NN/128)

typedef __bf16 bf16x8 __attribute__((ext_vector_type(8)));
typedef float f32x4 __attribute__((ext_vector_type(4)));

__device__ __forceinline__ float bflo(uint32_t u) { return __uint_as_float(u << 16); }
__device__ __forceinline__ float bfhi(uint32_t u) { return __uint_as_float(u & 0xffff0000u); }
__device__ __forceinline__ uint16_t f2bf(float f) {
    __hip_bfloat16 h = __float2bfloat16(f);
    return __builtin_bit_cast(uint16_t, h);
}
__device__ __forceinline__ uint32_t pack2(float lo, float hi) {
    return (uint32_t)f2bf(lo) | ((uint32_t)f2bf(hi) << 16);
}

// ---------------- CSR construction ----------------
__global__ void k_hist(const int* __restrict__ dstv, int* __restrict__ deg) {
    int e = blockIdx.x * 256 + threadIdx.x;
    if (e < NE) atomicAdd(&deg[dstv[e]], 1);
}

// single-pass scan: block-local exclusive prefix + atomic global base.
__global__ __launch_bounds__(512) void k_scan1(int* __restrict__ cursor /* deg in, rowbeg out */,
                                               int* __restrict__ rowptr,
                                               int* __restrict__ rowend,
                                               int* __restrict__ gcount) {
    __shared__ int s[512];
    __shared__ int base;
    int t = threadIdx.x;
    int i = blockIdx.x * 512 + t;
    int v = (i < NN) ? cursor[i] : 0;
    s[t] = v;
    __syncthreads();
    for (int st = 1; st < 512; st <<= 1) {
        int a = (t >= st) ? s[t - st] : 0;
        __syncthreads();
        s[t] += a;
        __syncthreads();
    }
    if (t == 511) base = atomicAdd(gcount, s[511]);
    __syncthreads();
    if (i < NN) {
        int b = base + s[t] - v;
        rowptr[i] = b;
        rowend[i] = b + v;
        cursor[i] = b;  // fill cursor
    }
}

__global__ void k_fill(const int* __restrict__ srcv, const int* __restrict__ dstv,
                       int* __restrict__ cursor, int* __restrict__ colv) {
    int e = blockIdx.x * 256 + threadIdx.x;
    if (e < NE) {
        int d = dstv[e];
        int p = atomicAdd(&cursor[d], 1);
        colv[p] = srcv[e];
    }
}

// ---------------- merged prep: weight convert + x->bf16 + cursor/gcount/bnsum zero ----------------
#define WCONV_BLOCKS 576  // 9*16384/256
__global__ void k_prep(const float* __restrict__ x, uint16_t* __restrict__ hb,
                       int* __restrict__ cursor, int* __restrict__ gcount,
                       float* __restrict__ bnsum,
                       const float* __restrict__ W1, const float* __restrict__ W2,
                       const float* __restrict__ Wl, uint16_t* __restrict__ Wb) {
    int b = blockIdx.x;
    if (b < WCONV_BLOCKS) {
        int id = b * 256 + threadIdx.x;
        int m = id >> 14;
        int r = id & 16383;
        int k = r >> 7;
        int col = r & 127;
        const float* src;
        if (m < 3) src = W1 + m * 16384;
        else if (m < 6) src = W2 + (m - 3) * 16384;
        else src = Wl + (m - 6) * 16384;
        float v = src[k * 128 + col];
        // image layout: [col][k] with k-index XOR-swizzled by (col&7)<<3 (bf16 units)
        Wb[m * 16384 + col * 128 + (k ^ ((col & 7) << 3))] = f2bf(v);
        return;
    }
    int id = (b - WCONV_BLOCKS) * 256 + threadIdx.x;
    if (id == 0) *gcount = 0;
    if (id < NL * 256) bnsum[id] = 0.f;  // per-layer BN stats slots
    if (id < NN) cursor[id] = 0;
    int base = id * 4;
    if (base >= NN * DD) return;
    float4 v = *(const float4*)(x + base);
    uint2 st;
    st.x = pack2(v.x, v.y);
    st.y = pack2(v.z, v.w);
    *(uint2*)(hb + base) = st;
}

// ---------------- aggregation: z = (1+eps)*h + sum_{src in N(dst)} h[src] ----------------
// 16 lanes per node, 4 nodes per wave, edge loop unrolled x4 (round-7-proven body).
#define ACC8(u) \
    a0 += bflo(u.x); a1 += bfhi(u.x); a2 += bflo(u.y); a3 += bfhi(u.y); \
    a4 += bflo(u.z); a5 += bfhi(u.z); a6 += bflo(u.w); a7 += bfhi(u.w);

__global__ __launch_bounds__(256) void k_agg(const uint16_t* __restrict__ hb,
                                             const int* __restrict__ rowptr,
                                             const int* __restrict__ rowend,
                                             const int* __restrict__ colv,
                                             const float* __restrict__ epsp, int layer,
                                             uint16_t* __restrict__ zb) {
    int g = (blockIdx.x * 256 + threadIdx.x) >> 4;  // node id
    int l16 = threadIdx.x & 15;
    if (g >= NN) return;
    float onepe = 1.0f + epsp[layer];
    int beg = rowptr[g], end = rowend[g];
    const uint4* hp = (const uint4*)hb;  // row = 16 uint4
    float a0 = 0.f, a1 = 0.f, a2 = 0.f, a3 = 0.f, a4 = 0.f, a5 = 0.f, a6 = 0.f, a7 = 0.f;
    int j = beg;
    for (; j + 3 < end; j += 4) {
        int s0 = colv[j];
        int s1 = colv[j + 1];
        int s2 = colv[j + 2];
        int s3 = colv[j + 3];
        uint4 u0 = hp[(size_t)s0 * 16 + l16];
        uint4 u1 = hp[(size_t)s1 * 16 + l16];
        uint4 u2 = hp[(size_t)s2 * 16 + l16];
        uint4 u3 = hp[(size_t)s3 * 16 + l16];
        ACC8(u0) ACC8(u1) ACC8(u2) ACC8(u3)
    }
    for (; j < end; ++j) {
        int s0 = colv[j];
        uint4 u = hp[(size_t)s0 * 16 + l16];
        ACC8(u)
    }
    uint4 hu = hp[(size_t)g * 16 + l16];
    a0 = fmaf(onepe, bflo(hu.x), a0); a1 = fmaf(onepe, bfhi(hu.x), a1);
    a2 = fmaf(onepe, bflo(hu.y), a2); a3 = fmaf(onepe, bfhi(hu.y), a3);
    a4 = fmaf(onepe, bflo(hu.z), a4); a5 = fmaf(onepe, bfhi(hu.z), a5);
    a6 = fmaf(onepe, bflo(hu.w), a6); a7 = fmaf(onepe, bfhi(hu.w), a7);
    uint4 st;
    st.x = pack2(a0, a1); st.y = pack2(a2, a3);
    st.z = pack2(a4, a5); st.w = pack2(a6, a7);
    ((uint4*)zb)[(size_t)g * 16 + l16] = st;
}

// ---------------- fused MLP: z2 = relu(zb @ W1 + b1) @ W2 + b2, + BN stats ----------------
// z2 stored as bf16 (stats computed from exact f32 acc before rounding).
// A-fragments prefetched to registers before LDS staging (no global loads in MFMA loop).
__global__ __launch_bounds__(256) void k_mlp(const uint16_t* __restrict__ A,
                                             const uint16_t* __restrict__ W1img,
                                             const uint16_t* __restrict__ W2img,
                                             const float* __restrict__ b1,
                                             const float* __restrict__ b2,
                                             float* __restrict__ bnsum,
                                             uint16_t* __restrict__ z2b) {
    __shared__ uint16_t ldsW[16384];  // 32KB
    __shared__ uint16_t ldsT[16384];  // 32KB
    int tid = threadIdx.x;
    int wid = tid >> 6, lane = tid & 63;

    const int brow = blockIdx.x * 128;
    const int m0 = wid * 32;
    const int l15 = lane & 15;
    const int lhi = lane >> 4;

    // prefetch A fragments for GEMM1 (128B/thread)
    bf16x8 afr[4][2];
    const char* Ab = (const char*)A;
#pragma unroll
    for (int kk = 0; kk < 4; ++kk) {
        int kbyte = kk * 64 + (lhi << 4);
#pragma unroll
        for (int m = 0; m < 2; ++m) {
            int row = brow + m0 + m * 16 + l15;
            if (row >= NN) row = NN - 1;
            afr[kk][m] = *(const bf16x8*)(Ab + (size_t)row * 256 + kbyte);
        }
    }

    // prefetch W2 image into registers (ds_write after GEMM1 barrier)
    bf16x8 w2r[8];
#pragma unroll
    for (int it = 0; it < 8; ++it) w2r[it] = *(const bf16x8*)(W2img + (it * 256 + tid) * 8);

    // stage W1 image
#pragma unroll
    for (int it = 0; it < 8; ++it) {
        int idx = (it * 256 + tid) * 8;
        *(bf16x8*)(&ldsW[idx]) = *(const bf16x8*)(W1img + idx);
    }
    __syncthreads();

    f32x4 acc[2][8];
    f32x4 zero = {0.f, 0.f, 0.f, 0.f};
#pragma unroll
    for (int m = 0; m < 2; ++m)
#pragma unroll
        for (int n = 0; n < 8; ++n) acc[m][n] = zero;

    // ---- GEMM1: A from regs ----
#pragma unroll
    for (int kk = 0; kk < 4; ++kk) {
        int kbyte = kk * 64 + (lhi << 4);
#pragma unroll
        for (int n = 0; n < 8; ++n) {
            int col = n * 16 + l15;
            int addr = col * 256 + (kbyte ^ ((col & 7) << 4));
            bf16x8 bfrag = *(const bf16x8*)((const char*)ldsW + addr);
            acc[0][n] = __builtin_amdgcn_mfma_f32_16x16x32_bf16(afr[kk][0], bfrag, acc[0][n], 0, 0, 0);
            acc[1][n] = __builtin_amdgcn_mfma_f32_16x16x32_bf16(afr[kk][1], bfrag, acc[1][n], 0, 0, 0);
        }
    }

    // ---- epilogue1: relu(acc + b1) -> ldsT (bf16, W-image layout) ----
    {
        float bc[8];
#pragma unroll
        for (int n = 0; n < 8; ++n) bc[n] = b1[n * 16 + l15];
#pragma unroll
        for (int m = 0; m < 2; ++m) {
            int rbase = m0 + m * 16 + (lhi << 2);  // local row
#pragma unroll
            for (int r = 0; r < 4; ++r) {
                int row = rbase + r;
#pragma unroll
                for (int n = 0; n < 8; ++n) {
                    float v = fmaxf(acc[m][n][r] + bc[n], 0.f);
                    int col = n * 16 + l15;
                    int byteoff = row * 256 + ((col * 2) ^ ((row & 7) << 4));
                    *(uint16_t*)((char*)ldsT + byteoff) = f2bf(v);
                }
            }
        }
    }
    __syncthreads();  // GEMM1 W1-reads done + t1 writes done

    // stage W2 from regs
#pragma unroll
    for (int it = 0; it < 8; ++it) *(bf16x8*)(&ldsW[(it * 256 + tid) * 8]) = w2r[it];
    __syncthreads();

    // ---- GEMM2: A from ldsT, B from ldsW ----
#pragma unroll
    for (int m = 0; m < 2; ++m)
#pragma unroll
        for (int n = 0; n < 8; ++n) acc[m][n] = zero;

#pragma unroll
    for (int kk = 0; kk < 4; ++kk) {
        int kbyte = kk * 64 + (lhi << 4);
        bf16x8 afrag[2];
#pragma unroll
        for (int m = 0; m < 2; ++m) {
            int rowl = m0 + m * 16 + l15;
            afrag[m] = *(const bf16x8*)((const char*)ldsT + rowl * 256 + (kbyte ^ ((rowl & 7) << 4)));
        }
#pragma unroll
        for (int n = 0; n < 8; ++n) {
            int col = n * 16 + l15;
            int addr = col * 256 + (kbyte ^ ((col & 7) << 4));
            bf16x8 bfrag = *(const bf16x8*)((const char*)ldsW + addr);
            acc[0][n] = __builtin_amdgcn_mfma_f32_16x16x32_bf16(afrag[0], bfrag, acc[0][n], 0, 0, 0);
            acc[1][n] = __builtin_amdgcn_mfma_f32_16x16x32_bf16(afrag[1], bfrag, acc[1][n], 0, 0, 0);
        }
    }

    // ---- epilogue2: z2 (bf16) + BN stats from exact f32 ----
    float bc2[8];
#pragma unroll
    for (int n = 0; n < 8; ++n) bc2[n] = b2[n * 16 + l15];

    float s1[8], s2[8];
#pragma unroll
    for (int n = 0; n < 8; ++n) { s1[n] = 0.f; s2[n] = 0.f; }

#pragma unroll
    for (int m = 0; m < 2; ++m) {
        int rbase = brow + m0 + m * 16 + (lhi << 2);
#pragma unroll
        for (int r = 0; r < 4; ++r) {
            int row = rbase + r;
            bool ok = row < NN;
#pragma unroll
            for (int n = 0; n < 8; ++n) {
                float v = acc[m][n][r] + bc2[n];
                if (ok) {
                    z2b[(size_t)row * 128 + n * 16 + l15] = f2bf(v);
                    s1[n] += v;
                    s2[n] += v * v;
                }
            }
        }
    }

    __syncthreads();  // ldsT A-reads done; reuse for stats
    float* ls = (float*)ldsT;
    ls[tid] = 0.f;
    __syncthreads();
#pragma unroll
    for (int n = 0; n < 8; ++n) {
        float a1 = s1[n] + __shfl_xor(s1[n], 16);
        a1 += __shfl_xor(a1, 32);
        float a2 = s2[n] + __shfl_xor(s2[n], 16);
        a2 += __shfl_xor(a2, 32);
        if (lane < 16) {
            atomicAdd(&ls[n * 16 + lane], a1);
            atomicAdd(&ls[128 + n * 16 + lane], a2);
        }
    }
    __syncthreads();
    atomicAdd(&bnsum[tid], ls[tid]);
}

// ---------------- BN finalize (per-block) + apply + skip + relu -> next h (bf16) ----------------
// 8 elems/thread, uint4 (16B) loads/stores; grid = NN*DD/8/256 = 3125 blocks exactly.
__global__ __launch_bounds__(256) void k_apply(const uint16_t* __restrict__ z2b,
                                               const uint16_t* __restrict__ hin,
                                               const float* __restrict__ bnsumL,
                                               const float* __restrict__ gammal,
                                               const float* __restrict__ betal, int has_skip,
                                               uint16_t* __restrict__ hout) {
    __shared__ float sA[128], sB[128];
    int tid = threadIdx.x;
    if (tid < 128) {
        float mu = bnsumL[tid] * (1.0f / NN);
        float var = bnsumL[128 + tid] * (1.0f / NN) - mu * mu;
        float a = gammal[tid] * rsqrtf(var + 1e-5f);
        sA[tid] = a;
        sB[tid] = betal[tid] - mu * a;
    }
    __syncthreads();
    size_t base = ((size_t)blockIdx.x * 256 + tid) * 8;
    int c = (int)(base & 127);
    uint4 zu = *(const uint4*)(z2b + base);
    float v0 = fmaf(sA[c + 0], bflo(zu.x), sB[c + 0]);
    float v1 = fmaf(sA[c + 1], bfhi(zu.x), sB[c + 1]);
    float v2 = fmaf(sA[c + 2], bflo(zu.y), sB[c + 2]);
    float v3 = fmaf(sA[c + 3], bfhi(zu.y), sB[c + 3]);
    float v4 = fmaf(sA[c + 4], bflo(zu.z), sB[c + 4]);
    float v5 = fmaf(sA[c + 5], bfhi(zu.z), sB[c + 5]);
    float v6 = fmaf(sA[c + 6], bflo(zu.w), sB[c + 6]);
    float v7 = fmaf(sA[c + 7], bfhi(zu.w), sB[c + 7]);
    if (has_skip) {
        uint4 h = *(const uint4*)(hin + base);
        v0 += bflo(h.x); v1 += bfhi(h.x);
        v2 += bflo(h.y); v3 += bfhi(h.y);
        v4 += bflo(h.z); v5 += bfhi(h.z);
        v6 += bflo(h.w); v7 += bfhi(h.w);
    }
    v0 = fmaxf(v0, 0.f); v1 = fmaxf(v1, 0.f); v2 = fmaxf(v2, 0.f); v3 = fmaxf(v3, 0.f);
    v4 = fmaxf(v4, 0.f); v5 = fmaxf(v5, 0.f); v6 = fmaxf(v6, 0.f); v7 = fmaxf(v7, 0.f);
    uint4 st;
    st.x = pack2(v0, v1);
    st.y = pack2(v2, v3);
    st.z = pack2(v4, v5);
    st.w = pack2(v6, v7);
    *(uint4*)(hout + base) = st;
}

// ---------------- batched output GEMMs: out[:, l*128:(l+1)*128] = h(l+1) @ Wl[l] + bl[l] ----------------
__global__ __launch_bounds__(256) void k_outgemm(const uint16_t* __restrict__ h1,
                                                 const uint16_t* __restrict__ h2,
                                                 const uint16_t* __restrict__ h3,
                                                 const uint16_t* __restrict__ Wb6,
                                                 const float* __restrict__ bl,
                                                 float* __restrict__ out) {
    __shared__ uint16_t lds[16384];
    int layer = blockIdx.x / GB;
    int blk = blockIdx.x - layer * GB;
    const uint16_t* A = (layer == 0) ? h1 : ((layer == 1) ? h2 : h3);
    const uint16_t* Wimg = Wb6 + layer * 16384;
    const float* bias = bl + layer * 128;

    int tid = threadIdx.x;
    int wid = tid >> 6, lane = tid & 63;
    const int brow = blk * 128;
    const int m0 = wid * 32;
    const int l15 = lane & 15;
    const int lhi = lane >> 4;

    // prefetch A fragments (128B/thread)
    bf16x8 afr[4][2];
    const char* Ab = (const char*)A;
#pragma unroll
    for (int kk = 0; kk < 4; ++kk) {
        int kbyte = kk * 64 + (lhi << 4);
#pragma unroll
        for (int m = 0; m < 2; ++m) {
            int row = brow + m0 + m * 16 + l15;
            if (row >= NN) row = NN - 1;
            afr[kk][m] = *(const bf16x8*)(Ab + (size_t)row * 256 + kbyte);
        }
    }

#pragma unroll
    for (int it = 0; it < 8; ++it) {
        int idx = (it * 256 + tid) * 8;
        bf16x8 v = *(const bf16x8*)(Wimg + idx);
        *(bf16x8*)(&lds[idx]) = v;
    }
    __syncthreads();

    f32x4 acc[2][8];
    f32x4 zero = {0.f, 0.f, 0.f, 0.f};
#pragma unroll
    for (int m = 0; m < 2; ++m)
#pragma unroll
        for (int n = 0; n < 8; ++n) acc[m][n] = zero;

#pragma unroll
    for (int kk = 0; kk < 4; ++kk) {
        int kbyte = kk * 64 + (lhi << 4);
#pragma unroll
        for (int n = 0; n < 8; ++n) {
            int col = n * 16 + l15;
            int addr = col * 256 + (kbyte ^ ((col & 7) << 4));
            bf16x8 bfrag = *(const bf16x8*)((const char*)lds + addr);
            acc[0][n] = __builtin_amdgcn_mfma_f32_16x16x32_bf16(afr[kk][0], bfrag, acc[0][n], 0, 0, 0);
            acc[1][n] = __builtin_amdgcn_mfma_f32_16x16x32_bf16(afr[kk][1], bfrag, acc[1][n], 0, 0, 0);
        }
    }

    float bcol[8];
#pragma unroll
    for (int n = 0; n < 8; ++n) bcol[n] = bias[n * 16 + l15];

#pragma unroll
    for (int m = 0; m < 2; ++m) {
        int rbase = brow + m0 + m * 16 + (lhi << 2);
#pragma unroll
        for (int r = 0; r < 4; ++r) {
            int row = rbase + r;
            if (row < NN) {
#pragma unroll
                for (int n = 0; n < 8; ++n) {
                    float v = acc[m][n][r] + bcol[n];
                    out[(size_t)row * (NL * DD) + layer * 128 + n * 16 + l15] = v;
                }
            }
        }
    }
}

extern "C" void kernel_launch(void* const* d_in, const int* in_sizes, int n_in,
                              void* d_out, int out_size, void* d_ws, size_t ws_size,
                              hipStream_t stream) {
    const float* x = (const float*)d_in[0];
    const int* ei = (const int*)d_in[1];
    const float* W1 = (const float*)d_in[2];
    const float* b1 = (const float*)d_in[3];
    const float* W2 = (const float*)d_in[4];
    const float* b2 = (const float*)d_in[5];
    const float* epsp = (const float*)d_in[6];
    const float* gamma = (const float*)d_in[7];
    const float* beta = (const float*)d_in[8];
    const float* Wl = (const float*)d_in[9];
    const float* bl = (const float*)d_in[10];
    float* out = (float*)d_out;

    char* w = (char*)d_ws;
    size_t off = 0;
    auto take = [&](size_t b) -> char* {
        char* p = w + off;
        off += (b + 255) & ~(size_t)255;
        return p;
    };
    uint16_t* hb[4];
    for (int i = 0; i < 4; ++i) hb[i] = (uint16_t*)take((size_t)NN * DD * 2);
    uint16_t* zb = (uint16_t*)take((size_t)NN * DD * 2);
    uint16_t* z2b = (uint16_t*)take((size_t)NN * DD * 2);
    int* rowptr = (int*)take((size_t)NN * 4);
    int* rowend = (int*)take((size_t)NN * 4);
    int* cursor = (int*)take((size_t)NN * 4);
    int* colv = (int*)take((size_t)NE * 4);
    uint16_t* Wb = (uint16_t*)take(9 * 16384 * 2);
    float* bnsum = (float*)take(NL * 256 * 4);
    int* gcount = (int*)take(256);

    const int* srcv = ei;        // edge_index[0]
    const int* dstv = ei + NE;   // edge_index[1]

    // merged prep: weight convert + x->bf16 + cursor/gcount/bnsum zero
    const int prep_tail_blocks = (NN * DD / 4 + 255) / 256;  // 6250
    k_prep<<<WCONV_BLOCKS + prep_tail_blocks, 256, 0, stream>>>(x, hb[0], cursor, gcount, bnsum,
                                                                W1, W2, Wl, Wb);

    // CSR build
    k_hist<<<(NE + 255) / 256, 256, 0, stream>>>(dstv, cursor);
    k_scan1<<<98, 512, 0, stream>>>(cursor, rowptr, rowend, gcount);
    k_fill<<<(NE + 255) / 256, 256, 0, stream>>>(srcv, dstv, cursor, colv);

    const int agg_blocks = (NN * 16 + 255) / 256;    // 3125
    const int apply_blocks = NN * DD / 8 / 256;      // 3125 exactly

    for (int l = 0; l < NL; ++l) {
        k_agg<<<agg_blocks, 256, 0, stream>>>(hb[l], rowptr, rowend, colv, epsp, l, zb);
        k_mlp<<<GB, 256, 0, stream>>>(zb, Wb + l * 16384, Wb + (3 + l) * 16384,
                                      b1 + l * 128, b2 + l * 128, bnsum + l * 256, z2b);
        k_apply<<<apply_blocks, 256, 0, stream>>>(z2b, hb[l], bnsum + l * 256,
                                                  gamma + l * 128, beta + l * 128,
                                                  l > 0 ? 1 : 0, hb[l + 1]);
    }
    k_outgemm<<<NL * GB, 256, 0, stream>>>(hb[1], hb[2], hb[3], Wb + 6 * 16384, bl, out);
}

// Round 11
// 259.464 us; speedup vs baseline: 1.2409x; 1.0027x over previous
//
#include <hip/hip_runtime.h>
#include <hip/hip_bf16.h>
#include <stdint.h>

#define NN 50000
#define NE 625000
#define DD 128
#define NL 3
#define GB 391  // gemm blocks = ceil(NN/128)

typedef __bf16 bf16x8 __attribute__((ext_vector_type(8)));
typedef float f32x4 __attribute__((ext_vector_type(4)));

__device__ __forceinline__ float bflo(uint32_t u) { return __uint_as_float(u << 16); }
__device__ __forceinline__ float bfhi(uint32_t u) { return __uint_as_float(u & 0xffff0000u); }
__device__ __forceinline__ uint16_t f2bf(float f) {
    __hip_bfloat16 h = __float2bfloat16(f);
    return __builtin_bit_cast(uint16_t, h);
}
__device__ __forceinline__ uint32_t pack2(float lo, float hi) {
    return (uint32_t)f2bf(lo) | ((uint32_t)f2bf(hi) << 16);
}

// ---------------- CSR construction ----------------
__global__ void k_hist(const int* __restrict__ dstv, int* __restrict__ deg) {
    int e = blockIdx.x * 256 + threadIdx.x;
    if (e < NE) atomicAdd(&deg[dstv[e]], 1);
}

// single-pass scan: block-local exclusive prefix + atomic global base.
__global__ __launch_bounds__(512) void k_scan1(int* __restrict__ cursor /* deg in, rowbeg out */,
                                               int* __restrict__ rowptr,
                                               int* __restrict__ rowend,
                                               int* __restrict__ gcount) {
    __shared__ int s[512];
    __shared__ int base;
    int t = threadIdx.x;
    int i = blockIdx.x * 512 + t;
    int v = (i < NN) ? cursor[i] : 0;
    s[t] = v;
    __syncthreads();
    for (int st = 1; st < 512; st <<= 1) {
        int a = (t >= st) ? s[t - st] : 0;
        __syncthreads();
        s[t] += a;
        __syncthreads();
    }
    if (t == 511) base = atomicAdd(gcount, s[511]);
    __syncthreads();
    if (i < NN) {
        int b = base + s[t] - v;
        rowptr[i] = b;
        rowend[i] = b + v;
        cursor[i] = b;  // fill cursor
    }
}

__global__ void k_fill(const int* __restrict__ srcv, const int* __restrict__ dstv,
                       int* __restrict__ cursor, int* __restrict__ colv) {
    int e = blockIdx.x * 256 + threadIdx.x;
    if (e < NE) {
        int d = dstv[e];
        int p = atomicAdd(&cursor[d], 1);
        colv[p] = srcv[e];
    }
}

// ---------------- merged prep: weight convert + x->bf16 + cursor/gcount/bnsum zero ----------------
#define WCONV_BLOCKS 576  // 9*16384/256
__global__ void k_prep(const float* __restrict__ x, uint16_t* __restrict__ hb,
                       int* __restrict__ cursor, int* __restrict__ gcount,
                       float* __restrict__ bnsum,
                       const float* __restrict__ W1, const float* __restrict__ W2,
                       const float* __restrict__ Wl, uint16_t* __restrict__ Wb) {
    int b = blockIdx.x;
    if (b < WCONV_BLOCKS) {
        int id = b * 256 + threadIdx.x;
        int m = id >> 14;
        int r = id & 16383;
        int k = r >> 7;
        int col = r & 127;
        const float* src;
        if (m < 3) src = W1 + m * 16384;
        else if (m < 6) src = W2 + (m - 3) * 16384;
        else src = Wl + (m - 6) * 16384;
        float v = src[k * 128 + col];
        // image layout: [col][k] with k-index XOR-swizzled by (col&7)<<3 (bf16 units)
        Wb[m * 16384 + col * 128 + (k ^ ((col & 7) << 3))] = f2bf(v);
        return;
    }
    int id = (b - WCONV_BLOCKS) * 256 + threadIdx.x;
    if (id == 0) *gcount = 0;
    if (id < NL * 256) bnsum[id] = 0.f;  // per-layer BN stats slots
    if (id < NN) cursor[id] = 0;
    int base = id * 4;
    if (base >= NN * DD) return;
    float4 v = *(const float4*)(x + base);
    uint2 st;
    st.x = pack2(v.x, v.y);
    st.y = pack2(v.z, v.w);
    *(uint2*)(hb + base) = st;
}

// ---------------- aggregation: z = (1+eps)*h + sum_{src in N(dst)} h[src] ----------------
// 16 lanes per node, 4 nodes per wave, edge loop unrolled x4 (round-7-proven body).
#define ACC8(u) \
    a0 += bflo(u.x); a1 += bfhi(u.x); a2 += bflo(u.y); a3 += bfhi(u.y); \
    a4 += bflo(u.z); a5 += bfhi(u.z); a6 += bflo(u.w); a7 += bfhi(u.w);

__global__ __launch_bounds__(256) void k_agg(const uint16_t* __restrict__ hb,
                                             const int* __restrict__ rowptr,
                                             const int* __restrict__ rowend,
                                             const int* __restrict__ colv,
                                             const float* __restrict__ epsp, int layer,
                                             uint16_t* __restrict__ zb) {
    int g = (blockIdx.x * 256 + threadIdx.x) >> 4;  // node id
    int l16 = threadIdx.x & 15;
    if (g >= NN) return;
    float onepe = 1.0f + epsp[layer];
    int beg = rowptr[g], end = rowend[g];
    const uint4* hp = (const uint4*)hb;  // row = 16 uint4
    float a0 = 0.f, a1 = 0.f, a2 = 0.f, a3 = 0.f, a4 = 0.f, a5 = 0.f, a6 = 0.f, a7 = 0.f;
    int j = beg;
    for (; j + 3 < end; j += 4) {
        int s0 = colv[j];
        int s1 = colv[j + 1];
        int s2 = colv[j + 2];
        int s3 = colv[j + 3];
        uint4 u0 = hp[(size_t)s0 * 16 + l16];
        uint4 u1 = hp[(size_t)s1 * 16 + l16];
        uint4 u2 = hp[(size_t)s2 * 16 + l16];
        uint4 u3 = hp[(size_t)s3 * 16 + l16];
        ACC8(u0) ACC8(u1) ACC8(u2) ACC8(u3)
    }
    for (; j < end; ++j) {
        int s0 = colv[j];
        uint4 u = hp[(size_t)s0 * 16 + l16];
        ACC8(u)
    }
    uint4 hu = hp[(size_t)g * 16 + l16];
    a0 = fmaf(onepe, bflo(hu.x), a0); a1 = fmaf(onepe, bfhi(hu.x), a1);
    a2 = fmaf(onepe, bflo(hu.y), a2); a3 = fmaf(onepe, bfhi(hu.y), a3);
    a4 = fmaf(onepe, bflo(hu.z), a4); a5 = fmaf(onepe, bfhi(hu.z), a5);
    a6 = fmaf(onepe, bflo(hu.w), a6); a7 = fmaf(onepe, bfhi(hu.w), a7);
    uint4 st;
    st.x = pack2(a0, a1); st.y = pack2(a2, a3);
    st.z = pack2(a4, a5); st.w = pack2(a6, a7);
    ((uint4*)zb)[(size_t)g * 16 + l16] = st;
}

// ---------------- fused MLP: z2 = relu(zb @ W1 + b1) @ W2 + b2, + BN stats ----------------
// 512 threads / 8 warps, 1 m-tile (16 rows) per warp: same 64KB LDS and 391 blocks,
// but 16 waves/CU (vs 8) for latency hiding; per-thread state halved.
__global__ __launch_bounds__(512) void k_mlp(const uint16_t* __restrict__ A,
                                             const uint16_t* __restrict__ W1img,
                                             const uint16_t* __restrict__ W2img,
                                             const float* __restrict__ b1,
                                             const float* __restrict__ b2,
                                             float* __restrict__ bnsum,
                                             uint16_t* __restrict__ z2b) {
    __shared__ uint16_t ldsW[16384];  // 32KB
    __shared__ uint16_t ldsT[16384];  // 32KB
    int tid = threadIdx.x;
    int wid = tid >> 6, lane = tid & 63;

    const int brow = blockIdx.x * 128;
    const int m0 = wid * 16;
    const int l15 = lane & 15;
    const int lhi = lane >> 4;

    // prefetch A fragments for GEMM1 (64B/thread)
    bf16x8 afr[4];
    {
        int arow = brow + m0 + l15;
        if (arow >= NN) arow = NN - 1;
        const char* Ab = (const char*)A;
#pragma unroll
        for (int kk = 0; kk < 4; ++kk)
            afr[kk] = *(const bf16x8*)(Ab + (size_t)arow * 256 + kk * 64 + (lhi << 4));
    }

    // prefetch W2 image into registers (ds_write after GEMM1 barrier)
    bf16x8 w2r[4];
#pragma unroll
    for (int it = 0; it < 4; ++it) w2r[it] = *(const bf16x8*)(W2img + (it * 512 + tid) * 8);

    // stage W1 image
#pragma unroll
    for (int it = 0; it < 4; ++it) {
        int idx = (it * 512 + tid) * 8;
        *(bf16x8*)(&ldsW[idx]) = *(const bf16x8*)(W1img + idx);
    }
    __syncthreads();

    f32x4 acc[8];
    f32x4 zero = {0.f, 0.f, 0.f, 0.f};
#pragma unroll
    for (int n = 0; n < 8; ++n) acc[n] = zero;

    // ---- GEMM1: A from regs, B = W1 ----
#pragma unroll
    for (int kk = 0; kk < 4; ++kk) {
        int kbyte = kk * 64 + (lhi << 4);
#pragma unroll
        for (int n = 0; n < 8; ++n) {
            int col = n * 16 + l15;
            int addr = col * 256 + (kbyte ^ ((col & 7) << 4));
            bf16x8 bfrag = *(const bf16x8*)((const char*)ldsW + addr);
            acc[n] = __builtin_amdgcn_mfma_f32_16x16x32_bf16(afr[kk], bfrag, acc[n], 0, 0, 0);
        }
    }

    // ---- epilogue1: relu(acc + b1) -> ldsT (bf16, W-image layout) ----
    {
        float bc[8];
#pragma unroll
        for (int n = 0; n < 8; ++n) bc[n] = b1[n * 16 + l15];
        int rbase = m0 + (lhi << 2);  // local row
#pragma unroll
        for (int r = 0; r < 4; ++r) {
            int row = rbase + r;
#pragma unroll
            for (int n = 0; n < 8; ++n) {
                float v = fmaxf(acc[n][r] + bc[n], 0.f);
                int col = n * 16 + l15;
                int byteoff = row * 256 + ((col * 2) ^ ((row & 7) << 4));
                *(uint16_t*)((char*)ldsT + byteoff) = f2bf(v);
            }
        }
    }
    __syncthreads();  // GEMM1 W1-reads done + t1 writes done

    // stage W2 from regs
#pragma unroll
    for (int it = 0; it < 4; ++it) *(bf16x8*)(&ldsW[(it * 512 + tid) * 8]) = w2r[it];
    __syncthreads();

    // ---- GEMM2: A from ldsT, B = W2 ----
#pragma unroll
    for (int n = 0; n < 8; ++n) acc[n] = zero;

#pragma unroll
    for (int kk = 0; kk < 4; ++kk) {
        int kbyte = kk * 64 + (lhi << 4);
        int rowl = m0 + l15;
        bf16x8 afrag = *(const bf16x8*)((const char*)ldsT + rowl * 256 + (kbyte ^ ((rowl & 7) << 4)));
#pragma unroll
        for (int n = 0; n < 8; ++n) {
            int col = n * 16 + l15;
            int addr = col * 256 + (kbyte ^ ((col & 7) << 4));
            bf16x8 bfrag = *(const bf16x8*)((const char*)ldsW + addr);
            acc[n] = __builtin_amdgcn_mfma_f32_16x16x32_bf16(afrag, bfrag, acc[n], 0, 0, 0);
        }
    }

    // ---- epilogue2: z2 (bf16) + BN stats from exact f32 ----
    float bc2[8];
#pragma unroll
    for (int n = 0; n < 8; ++n) bc2[n] = b2[n * 16 + l15];

    float s1[8], s2[8];
#pragma unroll
    for (int n = 0; n < 8; ++n) { s1[n] = 0.f; s2[n] = 0.f; }

    {
        int rbase = brow + m0 + (lhi << 2);
#pragma unroll
        for (int r = 0; r < 4; ++r) {
            int row = rbase + r;
            bool ok = row < NN;
#pragma unroll
            for (int n = 0; n < 8; ++n) {
                float v = acc[n][r] + bc2[n];
                if (ok) {
                    z2b[(size_t)row * 128 + n * 16 + l15] = f2bf(v);
                    s1[n] += v;
                    s2[n] += v * v;
                }
            }
        }
    }

    __syncthreads();  // ldsT A-reads done; reuse for stats
    float* ls = (float*)ldsT;
    if (tid < 256) ls[tid] = 0.f;
    __syncthreads();
#pragma unroll
    for (int n = 0; n < 8; ++n) {
        float a1 = s1[n] + __shfl_xor(s1[n], 16);
        a1 += __shfl_xor(a1, 32);
        float a2 = s2[n] + __shfl_xor(s2[n], 16);
        a2 += __shfl_xor(a2, 32);
        if (lane < 16) {
            atomicAdd(&ls[n * 16 + lane], a1);
            atomicAdd(&ls[128 + n * 16 + lane], a2);
        }
    }
    __syncthreads();
    if (tid < 256) atomicAdd(&bnsum[tid], ls[tid]);
}

// ---------------- BN finalize (per-block) + apply + skip + relu -> next h (bf16) ----------------
// 8 elems/thread, uint4 (16B) loads/stores; grid = NN*DD/8/256 = 3125 blocks exactly.
__global__ __launch_bounds__(256) void k_apply(const uint16_t* __restrict__ z2b,
                                               const uint16_t* __restrict__ hin,
                                               const float* __restrict__ bnsumL,
                                               const float* __restrict__ gammal,
                                               const float* __restrict__ betal, int has_skip,
                                               uint16_t* __restrict__ hout) {
    __shared__ float sA[128], sB[128];
    int tid = threadIdx.x;
    if (tid < 128) {
        float mu = bnsumL[tid] * (1.0f / NN);
        float var = bnsumL[128 + tid] * (1.0f / NN) - mu * mu;
        float a = gammal[tid] * rsqrtf(var + 1e-5f);
        sA[tid] = a;
        sB[tid] = betal[tid] - mu * a;
    }
    __syncthreads();
    size_t base = ((size_t)blockIdx.x * 256 + tid) * 8;
    int c = (int)(base & 127);
    uint4 zu = *(const uint4*)(z2b + base);
    float v0 = fmaf(sA[c + 0], bflo(zu.x), sB[c + 0]);
    float v1 = fmaf(sA[c + 1], bfhi(zu.x), sB[c + 1]);
    float v2 = fmaf(sA[c + 2], bflo(zu.y), sB[c + 2]);
    float v3 = fmaf(sA[c + 3], bfhi(zu.y), sB[c + 3]);
    float v4 = fmaf(sA[c + 4], bflo(zu.z), sB[c + 4]);
    float v5 = fmaf(sA[c + 5], bfhi(zu.z), sB[c + 5]);
    float v6 = fmaf(sA[c + 6], bflo(zu.w), sB[c + 6]);
    float v7 = fmaf(sA[c + 7], bfhi(zu.w), sB[c + 7]);
    if (has_skip) {
        uint4 h = *(const uint4*)(hin + base);
        v0 += bflo(h.x); v1 += bfhi(h.x);
        v2 += bflo(h.y); v3 += bfhi(h.y);
        v4 += bflo(h.z); v5 += bfhi(h.z);
        v6 += bflo(h.w); v7 += bfhi(h.w);
    }
    v0 = fmaxf(v0, 0.f); v1 = fmaxf(v1, 0.f); v2 = fmaxf(v2, 0.f); v3 = fmaxf(v3, 0.f);
    v4 = fmaxf(v4, 0.f); v5 = fmaxf(v5, 0.f); v6 = fmaxf(v6, 0.f); v7 = fmaxf(v7, 0.f);
    uint4 st;
    st.x = pack2(v0, v1);
    st.y = pack2(v2, v3);
    st.z = pack2(v4, v5);
    st.w = pack2(v6, v7);
    *(uint4*)(hout + base) = st;
}

// ---------------- batched output GEMMs (512 threads / 8 warps / 1 m-tile each) ----------------
__global__ __launch_bounds__(512) void k_outgemm(const uint16_t* __restrict__ h1,
                                                 const uint16_t* __restrict__ h2,
                                                 const uint16_t* __restrict__ h3,
                                                 const uint16_t* __restrict__ Wb6,
                                                 const float* __restrict__ bl,
                                                 float* __restrict__ out) {
    __shared__ uint16_t lds[16384];
    int layer = blockIdx.x / GB;
    int blk = blockIdx.x - layer * GB;
    const uint16_t* A = (layer == 0) ? h1 : ((layer == 1) ? h2 : h3);
    const uint16_t* Wimg = Wb6 + layer * 16384;
    const float* bias = bl + layer * 128;

    int tid = threadIdx.x;
    int wid = tid >> 6, lane = tid & 63;
    const int brow = blk * 128;
    const int m0 = wid * 16;
    const int l15 = lane & 15;
    const int lhi = lane >> 4;

    // prefetch A fragments (64B/thread)
    bf16x8 afr[4];
    {
        int arow = brow + m0 + l15;
        if (arow >= NN) arow = NN - 1;
        const char* Ab = (const char*)A;
#pragma unroll
        for (int kk = 0; kk < 4; ++kk)
            afr[kk] = *(const bf16x8*)(Ab + (size_t)arow * 256 + kk * 64 + (lhi << 4));
    }

#pragma unroll
    for (int it = 0; it < 4; ++it) {
        int idx = (it * 512 + tid) * 8;
        *(bf16x8*)(&lds[idx]) = *(const bf16x8*)(Wimg + idx);
    }
    __syncthreads();

    f32x4 acc[8];
    f32x4 zero = {0.f, 0.f, 0.f, 0.f};
#pragma unroll
    for (int n = 0; n < 8; ++n) acc[n] = zero;

#pragma unroll
    for (int kk = 0; kk < 4; ++kk) {
        int kbyte = kk * 64 + (lhi << 4);
#pragma unroll
        for (int n = 0; n < 8; ++n) {
            int col = n * 16 + l15;
            int addr = col * 256 + (kbyte ^ ((col & 7) << 4));
            bf16x8 bfrag = *(const bf16x8*)((const char*)lds + addr);
            acc[n] = __builtin_amdgcn_mfma_f32_16x16x32_bf16(afr[kk], bfrag, acc[n], 0, 0, 0);
        }
    }

    float bcol[8];
#pragma unroll
    for (int n = 0; n < 8; ++n) bcol[n] = bias[n * 16 + l15];

    {
        int rbase = brow + m0 + (lhi << 2);
#pragma unroll
        for (int r = 0; r < 4; ++r) {
            int row = rbase + r;
            if (row < NN) {
#pragma unroll
                for (int n = 0; n < 8; ++n) {
                    float v = acc[n][r] + bcol[n];
                    out[(size_t)row * (NL * DD) + layer * 128 + n * 16 + l15] = v;
                }
            }
        }
    }
}

extern "C" void kernel_launch(void* const* d_in, const int* in_sizes, int n_in,
                              void* d_out, int out_size, void* d_ws, size_t ws_size,
                              hipStream_t stream) {
    const float* x = (const float*)d_in[0];
    const int* ei = (const int*)d_in[1];
    const float* W1 = (const float*)d_in[2];
    const float* b1 = (const float*)d_in[3];
    const float* W2 = (const float*)d_in[4];
    const float* b2 = (const float*)d_in[5];
    const float* epsp = (const float*)d_in[6];
    const float* gamma = (const float*)d_in[7];
    const float* beta = (const float*)d_in[8];
    const float* Wl = (const float*)d_in[9];
    const float* bl = (const float*)d_in[10];
    float* out = (float*)d_out;

    char* w = (char*)d_ws;
    size_t off = 0;
    auto take = [&](size_t b) -> char* {
        char* p = w + off;
        off += (b + 255) & ~(size_t)255;
        return p;
    };
    uint16_t* hb[4];
    for (int i = 0; i < 4; ++i) hb[i] = (uint16_t*)take((size_t)NN * DD * 2);
    uint16_t* zb = (uint16_t*)take((size_t)NN * DD * 2);
    uint16_t* z2b = (uint16_t*)take((size_t)NN * DD * 2);
    int* rowptr = (int*)take((size_t)NN * 4);
    int* rowend = (int*)take((size_t)NN * 4);
    int* cursor = (int*)take((size_t)NN * 4);
    int* colv = (int*)take((size_t)NE * 4);
    uint16_t* Wb = (uint16_t*)take(9 * 16384 * 2);
    float* bnsum = (float*)take(NL * 256 * 4);
    int* gcount = (int*)take(256);

    const int* srcv = ei;        // edge_index[0]
    const int* dstv = ei + NE;   // edge_index[1]

    // merged prep: weight convert + x->bf16 + cursor/gcount/bnsum zero
    const int prep_tail_blocks = (NN * DD / 4 + 255) / 256;  // 6250
    k_prep<<<WCONV_BLOCKS + prep_tail_blocks, 256, 0, stream>>>(x, hb[0], cursor, gcount, bnsum,
                                                                W1, W2, Wl, Wb);

    // CSR build
    k_hist<<<(NE + 255) / 256, 256, 0, stream>>>(dstv, cursor);
    k_scan1<<<98, 512, 0, stream>>>(cursor, rowptr, rowend, gcount);
    k_fill<<<(NE + 255) / 256, 256, 0, stream>>>(srcv, dstv, cursor, colv);

    const int agg_blocks = (NN * 16 + 255) / 256;    // 3125
    const int apply_blocks = NN * DD / 8 / 256;      // 3125 exactly

    for (int l = 0; l < NL; ++l) {
        k_agg<<<agg_blocks, 256, 0, stream>>>(hb[l], rowptr, rowend, colv, epsp, l, zb);
        k_mlp<<<GB, 512, 0, stream>>>(zb, Wb + l * 16384, Wb + (3 + l) * 16384,
                                      b1 + l * 128, b2 + l * 128, bnsum + l * 256, z2b);
        k_apply<<<apply_blocks, 256, 0, stream>>>(z2b, hb[l], bnsum + l * 256,
                                                  gamma + l * 128, beta + l * 128,
                                                  l > 0 ? 1 : 0, hb[l + 1]);
    }
    k_outgemm<<<NL * GB, 512, 0, stream>>>(hb[1], hb[2], hb[3], Wb + 6 * 16384, bl, out);
}